// Round 1
// baseline (30218.918 us; speedup 1.0000x reference)
//
#include <hip/hip_runtime.h>
#include <math.h>

#define BATCH 4096
#define LATENT 256
#define H 512
#define A 64
#define SEQL 128
#define H3 1536

#define TILE 64
#define KT 16

enum { ACT_NONE = 0, ACT_TANH = 1 };

// C[M,N] = act(Ain[M,K] @ W[N,K]^T + bias[N])
// Ain row stride = lda, C row stride = ldc. M,N multiples of 64; K multiple of 16.
__global__ __launch_bounds__(256)
void linear_kernel(const float* __restrict__ Ain, int lda,
                   const float* __restrict__ W,
                   const float* __restrict__ bias,
                   float* __restrict__ C, int ldc,
                   int M, int N, int K, int act)
{
    __shared__ float As[KT][TILE];  // k-major: As[k][m]
    __shared__ float Ws[KT][TILE];  // k-major: Ws[k][n]

    const int tid = threadIdx.x;
    const int tx = tid & 15;        // 0..15 -> n quad
    const int ty = tid >> 4;        // 0..15 -> m quad
    const int n0 = blockIdx.x * TILE;
    const int m0 = blockIdx.y * TILE;

    const int lrow = tid >> 2;        // 0..63
    const int lcol = (tid & 3) * 4;   // 0,4,8,12

    float acc[4][4] = {};

    for (int k0 = 0; k0 < K; k0 += KT) {
        // global loads (issued before barrier so they overlap the wait)
        float4 av = *(const float4*)(Ain + (size_t)(m0 + lrow) * lda + k0 + lcol);
        float4 wv = *(const float4*)(W   + (size_t)(n0 + lrow) * K   + k0 + lcol);
        __syncthreads();            // previous iteration's reads complete
        As[lcol + 0][lrow] = av.x; As[lcol + 1][lrow] = av.y;
        As[lcol + 2][lrow] = av.z; As[lcol + 3][lrow] = av.w;
        Ws[lcol + 0][lrow] = wv.x; Ws[lcol + 1][lrow] = wv.y;
        Ws[lcol + 2][lrow] = wv.z; Ws[lcol + 3][lrow] = wv.w;
        __syncthreads();
#pragma unroll
        for (int k = 0; k < KT; ++k) {
            float4 a4 = *(const float4*)&As[k][ty * 4];
            float4 w4 = *(const float4*)&Ws[k][tx * 4];
            float aa[4] = {a4.x, a4.y, a4.z, a4.w};
            float ww[4] = {w4.x, w4.y, w4.z, w4.w};
#pragma unroll
            for (int i = 0; i < 4; ++i)
#pragma unroll
                for (int j = 0; j < 4; ++j)
                    acc[i][j] += aa[i] * ww[j];
        }
    }

#pragma unroll
    for (int i = 0; i < 4; ++i) {
        const int m = m0 + ty * 4 + i;
#pragma unroll
        for (int j = 0; j < 4; ++j) {
            const int n = n0 + tx * 4 + j;
            float v = acc[i][j] + bias[n];
            if (act == ACT_TANH) v = tanhf(v);
            C[(size_t)m * ldc + n] = v;
        }
    }
}

__global__ __launch_bounds__(256)
void gru_gates_kernel(const float* __restrict__ gi, const float* __restrict__ gh,
                      const float* __restrict__ h, float* __restrict__ hnew)
{
    int idx = blockIdx.x * blockDim.x + threadIdx.x;  // B*H threads
    int m = idx >> 9;          // /H
    int j = idx & (H - 1);
    const float* gim = gi + (size_t)m * H3;
    const float* ghm = gh + (size_t)m * H3;
    float ir = gim[j],       hr = ghm[j];
    float iz = gim[H + j],   hz = ghm[H + j];
    float in = gim[2*H + j], hn = ghm[2*H + j];
    float r = 1.0f / (1.0f + __expf(-(ir + hr)));
    float z = 1.0f / (1.0f + __expf(-(iz + hz)));
    float n = tanhf(in + r * hn);
    hnew[idx] = (1.0f - z) * n + z * h[idx];
}

// fill the BOS pseudo one-hot matrix [B,A] and write out[:,0,:]
__global__ __launch_bounds__(256)
void bos_kernel(float* __restrict__ bos, float* __restrict__ out)
{
    int idx = blockIdx.x * blockDim.x + threadIdx.x;  // B*A threads
    int a = idx & (A - 1);
    int m = idx >> 6;
    float v = (a == 0) ? 16.0f : -16.0f;
    bos[idx] = v;
    out[(size_t)m * SEQL * A + a] = v;
}

extern "C" void kernel_launch(void* const* d_in, const int* in_sizes, int n_in,
                              void* d_out, int out_size, void* d_ws, size_t ws_size,
                              hipStream_t stream)
{
    const float* latent = (const float*)d_in[0];
    const float* target = (const float*)d_in[1];
    const float* Wd1 = (const float*)d_in[2];
    const float* bd1 = (const float*)d_in[3];
    const float* Wd2 = (const float*)d_in[4];
    const float* bd2 = (const float*)d_in[5];
    const float* Wd3 = (const float*)d_in[6];
    const float* bd3 = (const float*)d_in[7];
    const float* W_ih = (const float*)d_in[8];
    const float* W_hh = (const float*)d_in[9];
    const float* b_ih = (const float*)d_in[10];
    const float* b_hh = (const float*)d_in[11];
    const float* Wm1 = (const float*)d_in[12];
    const float* bm1 = (const float*)d_in[13];
    const float* Wm2 = (const float*)d_in[14];
    const float* bm2 = (const float*)d_in[15];
    const float* Wm3 = (const float*)d_in[16];
    const float* bm3 = (const float*)d_in[17];

    float* out = (float*)d_out;
    float* ws = (float*)d_ws;

    // workspace carve (floats)
    float* bos = ws;                         // B*A
    float* tmp = bos + (size_t)BATCH * A;    // B*H
    float* h0  = tmp + (size_t)BATCH * H;    // B*H
    float* h1  = h0  + (size_t)BATCH * H;    // B*H
    float* gi  = h1  + (size_t)BATCH * H;    // B*3H
    float* gh  = gi  + (size_t)BATCH * H3;   // B*3H
    float* p1  = gh  + (size_t)BATCH * H3;   // B*H
    float* p2  = p1  + (size_t)BATCH * H;    // B*A

    dim3 blk(256);
    auto grid2 = [](int M, int N) { return dim3(N / TILE, M / TILE); };

    // initial MLP: latent -> tmp -> h1 -> h0
    linear_kernel<<<grid2(BATCH, H), blk, 0, stream>>>(latent, LATENT, Wd1, bd1, tmp, H, BATCH, H, LATENT, ACT_TANH);
    linear_kernel<<<grid2(BATCH, H), blk, 0, stream>>>(tmp, H, Wd2, bd2, h1, H, BATCH, H, H, ACT_TANH);
    linear_kernel<<<grid2(BATCH, H), blk, 0, stream>>>(h1, H, Wd3, bd3, h0, H, BATCH, H, H, ACT_NONE);

    // BOS matrix + out[:,0,:]
    bos_kernel<<<dim3(BATCH * A / 256), blk, 0, stream>>>(bos, out);

    float* h_cur = h0;
    float* h_nxt = h1;
    for (int t = 0; t < SEQL - 1; ++t) {
        const float* x = (t == 0) ? bos : (target + (size_t)t * A);
        int lda_x = (t == 0) ? A : (SEQL * A);

        // gi = x @ W_ih^T + b_ih      [B, 3H]
        linear_kernel<<<grid2(BATCH, H3), blk, 0, stream>>>(x, lda_x, W_ih, b_ih, gi, H3, BATCH, H3, A, ACT_NONE);
        // gh = h @ W_hh^T + b_hh      [B, 3H]
        linear_kernel<<<grid2(BATCH, H3), blk, 0, stream>>>(h_cur, H, W_hh, b_hh, gh, H3, BATCH, H3, H, ACT_NONE);
        // gates -> h_nxt
        gru_gates_kernel<<<dim3(BATCH * H / 256), blk, 0, stream>>>(gi, gh, h_cur, h_nxt);
        // per-step decoder
        linear_kernel<<<grid2(BATCH, H), blk, 0, stream>>>(h_nxt, H, Wm1, bm1, p1, H, BATCH, H, H, ACT_TANH);
        linear_kernel<<<grid2(BATCH, A), blk, 0, stream>>>(p1, H, Wm2, bm2, p2, A, BATCH, A, H, ACT_TANH);
        linear_kernel<<<grid2(BATCH, A), blk, 0, stream>>>(p2, A, Wm3, bm3, out + (size_t)(t + 1) * A, SEQL * A, BATCH, A, A, ACT_NONE);

        float* t2 = h_cur; h_cur = h_nxt; h_nxt = t2;
    }
}

// Round 2
// 4192.533 us; speedup vs baseline: 7.2078x; 7.2078x over previous
//
#include <hip/hip_runtime.h>
#include <math.h>
#include <stdint.h>

#define BATCH 4096
#define LATENT 256
#define H 512
#define A 64
#define SEQL 128
#define KCAT 576          // 64 (x) + 512 (h)
#define CT 8              // decoder time-chunk

typedef __bf16 bf16x8 __attribute__((ext_vector_type(8)));
typedef float f32x4 __attribute__((ext_vector_type(4)));

__device__ __forceinline__ uint16_t f2bf(float f) {
    union { float f; uint32_t u; } v; v.f = f;
    uint32_t u = v.u + 0x7FFFu + ((v.u >> 16) & 1u);
    return (uint16_t)(u >> 16);
}

__device__ __forceinline__ float fast_sig(float x) {
    return __fdividef(1.0f, 1.0f + __expf(-x));
}
__device__ __forceinline__ float fast_tanh(float x) {
    return __fdividef(2.0f, 1.0f + __expf(-2.0f * x)) - 1.0f;
}

__device__ __forceinline__ f32x4 mfma16(bf16x8 a, bf16x8 b, f32x4 c) {
    return __builtin_amdgcn_mfma_f32_16x16x32_bf16(a, b, c, 0, 0, 0);
}

__device__ __forceinline__ void load_lds16(const void* g, void* l) {
    __builtin_amdgcn_global_load_lds(
        (const __attribute__((address_space(1))) uint32_t*)g,
        (__attribute__((address_space(3))) uint32_t*)l, 16, 0, 0);
}

// ---------------- prep kernels ----------------

__global__ __launch_bounds__(256) void cvt_bf16_kernel(const float* __restrict__ src,
                                                       uint16_t* __restrict__ dst, int n) {
    int idx = (blockIdx.x * 256 + threadIdx.x) * 4;
    if (idx < n) {
        float4 v = *(const float4*)(src + idx);
        dst[idx + 0] = f2bf(v.x); dst[idx + 1] = f2bf(v.y);
        dst[idx + 2] = f2bf(v.z); dst[idx + 3] = f2bf(v.w);
    }
}

// Wcat[n][0:64] = W_ih[n][:], Wcat[n][64:576] = W_hh[n][:]   (n in [0,1536))
__global__ __launch_bounds__(256) void wcat_kernel(const float* __restrict__ W_ih,
                                                   const float* __restrict__ W_hh,
                                                   uint16_t* __restrict__ Wcat) {
    int idx = blockIdx.x * 256 + threadIdx.x;  // 1536*576
    if (idx < 1536 * KCAT) {
        int row = idx / KCAT, col = idx - row * KCAT;
        float v = (col < 64) ? W_ih[row * 64 + col] : W_hh[row * 512 + col - 64];
        Wcat[idx] = f2bf(v);
    }
}

// biases: br=b_ih[0:512]+b_hh[0:512], bz=..., bin=b_ih[1024:], bhn=b_hh[1024:]
__global__ __launch_bounds__(256) void bias_kernel(const float* __restrict__ b_ih,
                                                   const float* __restrict__ b_hh,
                                                   float* __restrict__ biases) {
    int idx = blockIdx.x * 256 + threadIdx.x;  // 2048
    if (idx < 2048) {
        int seg = idx >> 9, j = idx & 511;
        float v;
        if (seg == 0) v = b_ih[j] + b_hh[j];
        else if (seg == 1) v = b_ih[512 + j] + b_hh[512 + j];
        else if (seg == 2) v = b_ih[1024 + j];
        else v = b_hh[1024 + j];
        biases[idx] = v;
    }
}

__global__ __launch_bounds__(256) void bos_kernel(uint16_t* __restrict__ bosb,
                                                  float* __restrict__ out) {
    int idx = blockIdx.x * 256 + threadIdx.x;  // BATCH*A
    int a = idx & (A - 1);
    int b = idx >> 6;
    float v = (a == 0) ? 16.0f : -16.0f;
    bosb[idx] = f2bf(v);
    out[(size_t)b * SEQL * A + a] = v;
}

// ---------------- generic bf16 MFMA GEMM ----------------
// C[M,N] = act(Abf[M,K] @ Wbf[N,K]^T + bias[N])
// BM=128, BK=32, 256 threads (4 waves). flags: 1=tanh, 2=mapseq(out[b,t0+tloc+1,:])
template <int BN>
__global__ __launch_bounds__(256)
void gemm_kernel(const uint16_t* __restrict__ Abf, int lda,
                 const uint16_t* __restrict__ Wbf,
                 const float* __restrict__ bias,
                 uint16_t* __restrict__ outb, float* __restrict__ outf,
                 int ldc, int K, int flags, int t0)
{
    __shared__ __align__(16) uint16_t As[128 * 32];
    __shared__ __align__(16) uint16_t Bs[BN * 32];

    const int tid = threadIdx.x;
    const int w = tid >> 6, l = tid & 63;
    const int quad = l >> 4, lan = l & 15;
    const int m0 = blockIdx.y * 128;
    const int n0 = blockIdx.x * BN;

    constexpr int MI = (BN == 128) ? 4 : 2;
    const int wm = (BN == 128) ? ((w >> 1) * 64) : (w * 32);
    const int wn = (BN == 128) ? ((w & 1) * 64) : 0;

    f32x4 acc[MI][4];
#pragma unroll
    for (int i = 0; i < MI; ++i)
#pragma unroll
        for (int j = 0; j < 4; ++j) acc[i][j] = (f32x4){0.f, 0.f, 0.f, 0.f};

    const int arow = (l >> 2);       // 0..15 within wave-slice
    const int kc8 = (l & 3) * 8;     // element offset of 16B chunk

    for (int k0 = 0; k0 < K; k0 += 32) {
        __syncthreads();
#pragma unroll
        for (int i = 0; i < 2; ++i) {
            int row = i * 64 + w * 16 + arow;
            load_lds16(Abf + (size_t)(m0 + row) * lda + k0 + kc8,
                       As + i * 2048 + w * 512 + l * 8);
        }
#pragma unroll
        for (int i = 0; i < BN / 64; ++i) {
            int row = i * 64 + w * 16 + arow;
            load_lds16(Wbf + (size_t)(n0 + row) * K + k0 + kc8,
                       Bs + i * 2048 + w * 512 + l * 8);
        }
        __syncthreads();

        bf16x8 af[MI], bf[4];
#pragma unroll
        for (int mi = 0; mi < MI; ++mi)
            af[mi] = *(const bf16x8*)(As + (wm + mi * 16 + lan) * 32 + quad * 8);
#pragma unroll
        for (int nj = 0; nj < 4; ++nj)
            bf[nj] = *(const bf16x8*)(Bs + (wn + nj * 16 + lan) * 32 + quad * 8);
#pragma unroll
        for (int mi = 0; mi < MI; ++mi)
#pragma unroll
            for (int nj = 0; nj < 4; ++nj)
                acc[mi][nj] = mfma16(af[mi], bf[nj], acc[mi][nj]);
    }

    const bool do_tanh = flags & 1;
    const bool mapseq = flags & 2;
#pragma unroll
    for (int mi = 0; mi < MI; ++mi) {
#pragma unroll
        for (int nj = 0; nj < 4; ++nj) {
#pragma unroll
            for (int reg = 0; reg < 4; ++reg) {
                int m = m0 + wm + mi * 16 + quad * 4 + reg;
                int n = n0 + wn + nj * 16 + lan;
                float v = acc[mi][nj][reg] + bias[n];
                if (do_tanh) v = fast_tanh(v);
                if (mapseq) {
                    int b = m & (BATCH - 1), tloc = m >> 12;
                    outf[(size_t)b * SEQL * A + (size_t)(t0 + tloc + 1) * A + n] = v;
                } else {
                    if (outf) outf[(size_t)m * ldc + n] = v;
                    if (outb) outb[(size_t)m * ldc + n] = f2bf(v);
                }
            }
        }
    }
}

// ---------------- fused GRU step ----------------
// gates = [x|h] @ Wcat^T ; r,z over full K; in over x-K; hn over h-K.
// BM=64 rows, N-group = 64 cols of each of r/z/n. 128 threads (2 waves).
__global__ __launch_bounds__(128)
void gru_step_kernel(const uint16_t* __restrict__ xsrc, int sx,
                     const uint16_t* __restrict__ hsrc,       // bf16 h_t, stride H
                     const uint16_t* __restrict__ Wcat,       // [1536][576]
                     const float* __restrict__ biases,        // br,bz,bin,bhn
                     const float* __restrict__ hprev,         // fp32 [B][H]
                     float* __restrict__ hout_f,
                     uint16_t* __restrict__ hout_b)
{
    __shared__ __align__(16) uint16_t As[64 * 32];
    __shared__ __align__(16) uint16_t Bs[192 * 32];

    const int tid = threadIdx.x;
    const int w = tid >> 6, l = tid & 63;
    const int quad = l >> 4, lan = l & 15;
    const int m0 = blockIdx.y * 64;
    const int j0 = blockIdx.x * 64;

    f32x4 acc[2][4][4];  // [mi][group r,z,in,hn][nj]
#pragma unroll
    for (int a = 0; a < 2; ++a)
#pragma unroll
        for (int b = 0; b < 4; ++b)
#pragma unroll
            for (int c = 0; c < 4; ++c) acc[a][b][c] = (f32x4){0.f, 0.f, 0.f, 0.f};

    const int arow = (l >> 2);
    const int kc8 = (l & 3) * 8;

    for (int it = 0; it < KCAT / 32; ++it) {
        const int k0 = it * 32;
        const bool xseg = (k0 < 64);
        __syncthreads();
        {
            const uint16_t* src = xseg ? xsrc : hsrc;
            const int stride = xseg ? sx : H;
            const int kc = xseg ? k0 : (k0 - 64);
#pragma unroll
            for (int i = 0; i < 2; ++i) {
                int row = i * 32 + w * 16 + arow;
                load_lds16(src + (size_t)(m0 + row) * stride + kc + kc8,
                           As + i * 1024 + w * 512 + l * 8);
            }
        }
#pragma unroll
        for (int i = 0; i < 6; ++i) {
            int row = i * 32 + w * 16 + arow;        // 0..191
            int g = row >> 6, n = row & 63;
            load_lds16(Wcat + (size_t)((g << 9) + j0 + n) * KCAT + k0 + kc8,
                       Bs + i * 1024 + w * 512 + l * 8);
        }
        __syncthreads();

        bf16x8 af[2];
#pragma unroll
        for (int mi = 0; mi < 2; ++mi)
            af[mi] = *(const bf16x8*)(As + (w * 32 + mi * 16 + lan) * 32 + quad * 8);
#pragma unroll
        for (int g = 0; g < 3; ++g) {
            const int tgt = (g == 2) ? (xseg ? 2 : 3) : g;
#pragma unroll
            for (int nj = 0; nj < 4; ++nj) {
                bf16x8 bfr = *(const bf16x8*)(Bs + (g * 64 + nj * 16 + lan) * 32 + quad * 8);
                acc[0][tgt][nj] = mfma16(af[0], bfr, acc[0][tgt][nj]);
                acc[1][tgt][nj] = mfma16(af[1], bfr, acc[1][tgt][nj]);
            }
        }
    }

    const float* br = biases;
    const float* bz = biases + 512;
    const float* bi = biases + 1024;
    const float* bh = biases + 1536;
#pragma unroll
    for (int mi = 0; mi < 2; ++mi) {
#pragma unroll
        for (int nj = 0; nj < 4; ++nj) {
#pragma unroll
            for (int reg = 0; reg < 4; ++reg) {
                int m = m0 + w * 32 + mi * 16 + quad * 4 + reg;
                int j = j0 + nj * 16 + lan;
                float R = acc[mi][0][nj][reg] + br[j];
                float Z = acc[mi][1][nj][reg] + bz[j];
                float I = acc[mi][2][nj][reg] + bi[j];
                float Hh = acc[mi][3][nj][reg] + bh[j];
                float r = fast_sig(R);
                float z = fast_sig(Z);
                float nn = fast_tanh(I + r * Hh);
                float hp = hprev[(size_t)m * H + j];
                float hv = (1.0f - z) * nn + z * hp;
                hout_f[(size_t)m * H + j] = hv;
                hout_b[(size_t)m * H + j] = f2bf(hv);
            }
        }
    }
}

// ---------------- host ----------------

extern "C" void kernel_launch(void* const* d_in, const int* in_sizes, int n_in,
                              void* d_out, int out_size, void* d_ws, size_t ws_size,
                              hipStream_t stream)
{
    const float* latent = (const float*)d_in[0];
    const float* target = (const float*)d_in[1];
    const float* Wd1 = (const float*)d_in[2];
    const float* bd1 = (const float*)d_in[3];
    const float* Wd2 = (const float*)d_in[4];
    const float* bd2 = (const float*)d_in[5];
    const float* Wd3 = (const float*)d_in[6];
    const float* bd3 = (const float*)d_in[7];
    const float* W_ih = (const float*)d_in[8];
    const float* W_hh = (const float*)d_in[9];
    const float* b_ih = (const float*)d_in[10];
    const float* b_hh = (const float*)d_in[11];
    const float* Wm1 = (const float*)d_in[12];
    const float* bm1 = (const float*)d_in[13];
    const float* Wm2 = (const float*)d_in[14];
    const float* bm2 = (const float*)d_in[15];
    const float* Wm3 = (const float*)d_in[16];
    const float* bm3 = (const float*)d_in[17];

    float* out = (float*)d_out;
    uint8_t* ws = (uint8_t*)d_ws;

    // workspace carve (bytes, 256-aligned)
    size_t off = 0;
    auto carve = [&](size_t bytes) { void* p = ws + off; off += (bytes + 255) & ~(size_t)255; return p; };
    uint16_t* latb = (uint16_t*)carve((size_t)BATCH * LATENT * 2);
    uint16_t* wd1b = (uint16_t*)carve((size_t)H * LATENT * 2);
    uint16_t* wd2b = (uint16_t*)carve((size_t)H * H * 2);
    uint16_t* wd3b = (uint16_t*)carve((size_t)H * H * 2);
    uint16_t* wm1b = (uint16_t*)carve((size_t)H * H * 2);
    uint16_t* wm2b = (uint16_t*)carve((size_t)A * H * 2);
    uint16_t* wm3b = (uint16_t*)carve((size_t)A * A * 2);
    uint16_t* wcat = (uint16_t*)carve((size_t)1536 * KCAT * 2);
    float* biases  = (float*)carve(2048 * 4);
    uint16_t* bosb = (uint16_t*)carve((size_t)BATCH * A * 2);
    uint16_t* xbf  = (uint16_t*)carve((size_t)BATCH * SEQL * A * 2);
    uint16_t* t1b  = (uint16_t*)carve((size_t)BATCH * H * 2);
    uint16_t* t2b  = (uint16_t*)carve((size_t)BATCH * H * 2);
    uint16_t* h0bf = (uint16_t*)carve((size_t)BATCH * H * 2);
    float* hA      = (float*)carve((size_t)BATCH * H * 4);
    float* hB      = (float*)carve((size_t)BATCH * H * 4);
    uint16_t* hall = (uint16_t*)carve((size_t)CT * BATCH * H * 2);
    uint16_t* p1   = (uint16_t*)carve((size_t)CT * BATCH * H * 2);
    uint16_t* p2   = (uint16_t*)carve((size_t)CT * BATCH * A * 2);
    float* hbuf[2] = {hA, hB};

    dim3 blk256(256), blk128(128);

    // ---- prep ----
    auto cvt = [&](const float* s, uint16_t* d, int n) {
        cvt_bf16_kernel<<<dim3((n / 4 + 255) / 256), blk256, 0, stream>>>(s, d, n);
    };
    cvt(latent, latb, BATCH * LATENT);
    cvt(Wd1, wd1b, H * LATENT);
    cvt(Wd2, wd2b, H * H);
    cvt(Wd3, wd3b, H * H);
    cvt(Wm1, wm1b, H * H);
    cvt(Wm2, wm2b, A * H);
    cvt(Wm3, wm3b, A * A);
    cvt(target, xbf, BATCH * SEQL * A);
    wcat_kernel<<<dim3((1536 * KCAT + 255) / 256), blk256, 0, stream>>>(W_ih, W_hh, wcat);
    bias_kernel<<<dim3(8), blk256, 0, stream>>>(b_ih, b_hh, biases);
    bos_kernel<<<dim3(BATCH * A / 256), blk256, 0, stream>>>(bosb, out);

    // ---- initial MLP (latent -> h0) ----
    gemm_kernel<128><<<dim3(H / 128, BATCH / 128), blk256, 0, stream>>>(
        latb, LATENT, wd1b, bd1, t1b, nullptr, H, LATENT, 1, 0);
    gemm_kernel<128><<<dim3(H / 128, BATCH / 128), blk256, 0, stream>>>(
        t1b, H, wd2b, bd2, t2b, nullptr, H, H, 1, 0);
    gemm_kernel<128><<<dim3(H / 128, BATCH / 128), blk256, 0, stream>>>(
        t2b, H, wd3b, bd3, h0bf, hbuf[0], H, H, 0, 0);

    // ---- recurrence + chunked decoder ----
    for (int t = 0; t < SEQL - 1; ++t) {
        const uint16_t* xsrc = (t == 0) ? bosb : (xbf + (size_t)t * A);
        const int sx = (t == 0) ? A : (SEQL * A);
        const uint16_t* hsrc = (t == 0) ? h0bf : (hall + (size_t)((t - 1) % CT) * BATCH * H);
        uint16_t* houtb = hall + (size_t)(t % CT) * BATCH * H;

        gru_step_kernel<<<dim3(H / 64, BATCH / 64), blk128, 0, stream>>>(
            xsrc, sx, hsrc, wcat, biases, hbuf[t & 1], hbuf[(t + 1) & 1], houtb);

        if ((t % CT) == CT - 1 || t == SEQL - 2) {
            const int t0c = (t / CT) * CT;
            const int ctc = t - t0c + 1;
            const int M = ctc * BATCH;
            // d1 = tanh(h_chunk @ Wm1^T)  [M,512]
            gemm_kernel<128><<<dim3(H / 128, M / 128), blk256, 0, stream>>>(
                hall, H, wm1b, bm1, p1, nullptr, H, H, 1, 0);
            // d2 = tanh(p1 @ Wm2^T)  [M,64]
            gemm_kernel<64><<<dim3(1, M / 128), blk256, 0, stream>>>(
                p1, H, wm2b, bm2, p2, nullptr, A, H, 1, 0);
            // d3 = p2 @ Wm3^T -> out[b, t0+tloc+1, :]
            gemm_kernel<64><<<dim3(1, M / 128), blk256, 0, stream>>>(
                p2, A, wm3b, bm3, nullptr, out, A, A, 2, t0c);
        }
    }
}

// Round 3
// 3555.032 us; speedup vs baseline: 8.5003x; 1.1793x over previous
//
#include <hip/hip_runtime.h>
#include <math.h>
#include <stdint.h>

#define BATCH 4096
#define LATENT 256
#define H 512
#define A 64
#define SEQL 128
#define KCAT 576          // 64 (x) + 512 (h)
#define CT 8              // decoder time-chunk
#define NSTEP 127

typedef __bf16 bf16x8 __attribute__((ext_vector_type(8)));
typedef float f32x4 __attribute__((ext_vector_type(4)));

__device__ __forceinline__ uint16_t f2bf(float f) {
    union { float f; uint32_t u; } v; v.f = f;
    uint32_t u = v.u + 0x7FFFu + ((v.u >> 16) & 1u);
    return (uint16_t)(u >> 16);
}

__device__ __forceinline__ float fast_sig(float x) {
    return __fdividef(1.0f, 1.0f + __expf(-x));
}
__device__ __forceinline__ float fast_tanh(float x) {
    return __fdividef(2.0f, 1.0f + __expf(-2.0f * x)) - 1.0f;
}

__device__ __forceinline__ f32x4 mfma16(bf16x8 a, bf16x8 b, f32x4 c) {
    return __builtin_amdgcn_mfma_f32_16x16x32_bf16(a, b, c, 0, 0, 0);
}

__device__ __forceinline__ void load_lds16(const void* g, void* l) {
    __builtin_amdgcn_global_load_lds(
        (const __attribute__((address_space(1))) uint32_t*)g,
        (__attribute__((address_space(3))) uint32_t*)l, 16, 0, 0);
}

// ---------------- prep kernels ----------------

__global__ __launch_bounds__(256) void cvt_bf16_kernel(const float* __restrict__ src,
                                                       uint16_t* __restrict__ dst, int n) {
    int idx = (blockIdx.x * 256 + threadIdx.x) * 4;
    if (idx < n) {
        float4 v = *(const float4*)(src + idx);
        dst[idx + 0] = f2bf(v.x); dst[idx + 1] = f2bf(v.y);
        dst[idx + 2] = f2bf(v.z); dst[idx + 3] = f2bf(v.w);
    }
}

// Wcat[n][0:64] = W_ih[n][:], Wcat[n][64:576] = W_hh[n][:]   (n in [0,1536))
__global__ __launch_bounds__(256) void wcat_kernel(const float* __restrict__ W_ih,
                                                   const float* __restrict__ W_hh,
                                                   uint16_t* __restrict__ Wcat) {
    int idx = blockIdx.x * 256 + threadIdx.x;  // 1536*576
    if (idx < 1536 * KCAT) {
        int row = idx / KCAT, col = idx - row * KCAT;
        float v = (col < 64) ? W_ih[row * 64 + col] : W_hh[row * 512 + col - 64];
        Wcat[idx] = f2bf(v);
    }
}

// biases[2048]: br=b_ih[0:512]+b_hh[0:512], bz=..., bin=b_ih[1024:], bhn=b_hh[1024:]
__global__ __launch_bounds__(256) void bias_kernel(const float* __restrict__ b_ih,
                                                   const float* __restrict__ b_hh,
                                                   float* __restrict__ biases) {
    int idx = blockIdx.x * 256 + threadIdx.x;  // 2048
    if (idx < 2048) {
        int seg = idx >> 9, j = idx & 511;
        float v;
        if (seg == 0) v = b_ih[j] + b_hh[j];
        else if (seg == 1) v = b_ih[512 + j] + b_hh[512 + j];
        else if (seg == 2) v = b_ih[1024 + j];
        else v = b_hh[1024 + j];
        biases[idx] = v;
    }
}

// X_all[t][b][a]: t==0 -> bos pseudo one-hot; t>=1 -> target[b][t][a]   (bf16)
__global__ __launch_bounds__(256) void xall_kernel(const float* __restrict__ target,
                                                   uint16_t* __restrict__ X) {
    int idx = blockIdx.x * 256 + threadIdx.x;
    int e = idx * 4;                 // NSTEP*BATCH*A total elems, grid exact
    int a = e & 63;
    int b = (e >> 6) & (BATCH - 1);
    int t = e >> 18;
    ushort4 o;
    if (t == 0) {
        o.x = f2bf((a == 0) ? 16.0f : -16.0f);
        uint16_t m16 = f2bf(-16.0f);
        o.y = m16; o.z = m16; o.w = m16;
    } else {
        float4 v = *(const float4*)(target + ((size_t)b * SEQL + t) * A + a);
        o.x = f2bf(v.x); o.y = f2bf(v.y); o.z = f2bf(v.z); o.w = f2bf(v.w);
    }
    *(ushort4*)(X + e) = o;
}

__global__ __launch_bounds__(256) void bosout_kernel(float* __restrict__ out) {
    int idx = blockIdx.x * 256 + threadIdx.x;  // BATCH*A
    int a = idx & (A - 1);
    int b = idx >> 6;
    out[(size_t)b * SEQL * A + a] = (a == 0) ? 16.0f : -16.0f;
}

// ---------------- generic bf16 MFMA GEMM ----------------
// C[M,N] = act(Abf[M,K] @ Wbf[N,K]^T + bias[N]); BM=128, BN=128, BK=32, 256 thr.
__global__ __launch_bounds__(256)
void gemm_kernel(const uint16_t* __restrict__ Abf, int lda,
                 const uint16_t* __restrict__ Wbf,
                 const float* __restrict__ bias,
                 uint16_t* __restrict__ outb, float* __restrict__ outf,
                 int ldc, int K, int do_tanh)
{
    __shared__ __align__(16) uint16_t As[128 * 32];
    __shared__ __align__(16) uint16_t Bs[128 * 32];

    const int tid = threadIdx.x;
    const int w = tid >> 6, l = tid & 63;
    const int quad = l >> 4, lan = l & 15;
    const int m0 = blockIdx.y * 128;
    const int n0 = blockIdx.x * 128;
    const int wm = (w >> 1) * 64;
    const int wn = (w & 1) * 64;

    f32x4 acc[4][4];
#pragma unroll
    for (int i = 0; i < 4; ++i)
#pragma unroll
        for (int j = 0; j < 4; ++j) acc[i][j] = (f32x4){0.f, 0.f, 0.f, 0.f};

    const int arow = (l >> 2);
    const int kc8 = (l & 3) * 8;

    for (int k0 = 0; k0 < K; k0 += 32) {
        __syncthreads();
#pragma unroll
        for (int i = 0; i < 2; ++i) {
            int row = i * 64 + w * 16 + arow;
            load_lds16(Abf + (size_t)(m0 + row) * lda + k0 + kc8,
                       As + i * 2048 + w * 512 + l * 8);
        }
#pragma unroll
        for (int i = 0; i < 2; ++i) {
            int row = i * 64 + w * 16 + arow;
            load_lds16(Wbf + (size_t)(n0 + row) * K + k0 + kc8,
                       Bs + i * 2048 + w * 512 + l * 8);
        }
        __syncthreads();

        bf16x8 af[4], bf[4];
#pragma unroll
        for (int mi = 0; mi < 4; ++mi)
            af[mi] = *(const bf16x8*)(As + (wm + mi * 16 + lan) * 32 + quad * 8);
#pragma unroll
        for (int nj = 0; nj < 4; ++nj)
            bf[nj] = *(const bf16x8*)(Bs + (wn + nj * 16 + lan) * 32 + quad * 8);
#pragma unroll
        for (int mi = 0; mi < 4; ++mi)
#pragma unroll
            for (int nj = 0; nj < 4; ++nj)
                acc[mi][nj] = mfma16(af[mi], bf[nj], acc[mi][nj]);
    }

#pragma unroll
    for (int mi = 0; mi < 4; ++mi) {
#pragma unroll
        for (int nj = 0; nj < 4; ++nj) {
#pragma unroll
            for (int reg = 0; reg < 4; ++reg) {
                int m = m0 + wm + mi * 16 + quad * 4 + reg;
                int n = n0 + wn + nj * 16 + lan;
                float v = acc[mi][nj][reg] + bias[n];
                if (do_tanh) v = fast_tanh(v);
                if (outf) outf[(size_t)m * ldc + n] = v;
                if (outb) outb[(size_t)m * ldc + n] = f2bf(v);
            }
        }
    }
}

// ---------------- fused GRU step ----------------
// [x|h] @ Wcat^T with gate epilogue. Block: 128 m x 32 j (96 gate cols), 4 waves.
// Wave: 64 m x 48 gc (mi=4; r,z,n of 16 j each). K=576 (2 x-iters + 16 h-iters).
__global__ __launch_bounds__(256)
void gru_step_kernel(const uint16_t* __restrict__ xb,    // [4096][64] step's x
                     const uint16_t* __restrict__ hbf,   // [4096][512] h bf16
                     const uint16_t* __restrict__ Wcat,  // [1536][576]
                     const float* __restrict__ biases,   // br,bz,bin,bhn
                     const float* __restrict__ hprev,    // fp32 [4096][512]
                     float* __restrict__ hout_f,
                     uint16_t* __restrict__ hout_b)
{
    __shared__ __align__(16) uint16_t As[128 * 32];  // 8 KB
    __shared__ __align__(16) uint16_t Bs[96 * 32];   // 6 KB

    const int tid = threadIdx.x;
    const int w = tid >> 6, l = tid & 63;
    const int quad = l >> 4, lan = l & 15;
    const int m0 = blockIdx.y * 128;
    const int j0 = blockIdx.x * 32;
    const int wm = (w >> 1) * 64;
    const int wj = (w & 1) * 16;

    f32x4 acc[4][4];  // [mi][r, z, in, hn]
#pragma unroll
    for (int i = 0; i < 4; ++i)
#pragma unroll
        for (int j = 0; j < 4; ++j) acc[i][j] = (f32x4){0.f, 0.f, 0.f, 0.f};

    for (int it = 0; it < KCAT / 32; ++it) {
        const int k0 = it * 32;
        const bool xseg = (k0 < 64);
        __syncthreads();
        // A staging: 512 x 16B chunks, 2 per thread
#pragma unroll
        for (int i = 0; i < 2; ++i) {
            int g = i * 256 + tid;
            int row = g >> 2, kc = (g & 3) * 8;
            const uint16_t* src = xseg
                ? (xb  + (size_t)(m0 + row) * 64  + k0 + kc)
                : (hbf + (size_t)(m0 + row) * 512 + (k0 - 64) + kc);
            load_lds16(src, As + (size_t)g * 8);
        }
        // B staging: 384 chunks (96 gate rows x 32 k)
        {
            int g = tid;
            int row = g >> 2, kc = (g & 3) * 8;
            int wrow = ((row >> 5) << 9) + j0 + (row & 31);
            load_lds16(Wcat + (size_t)wrow * KCAT + k0 + kc, Bs + (size_t)g * 8);
        }
        if (w < 2) {
            int g = 256 + tid;
            int row = g >> 2, kc = (g & 3) * 8;
            int wrow = ((row >> 5) << 9) + j0 + (row & 31);
            load_lds16(Wcat + (size_t)wrow * KCAT + k0 + kc, Bs + (size_t)g * 8);
        }
        __syncthreads();

        bf16x8 af[4], bfr[3];
#pragma unroll
        for (int mi = 0; mi < 4; ++mi)
            af[mi] = *(const bf16x8*)(As + (wm + mi * 16 + lan) * 32 + quad * 8);
#pragma unroll
        for (int g = 0; g < 3; ++g)
            bfr[g] = *(const bf16x8*)(Bs + (g * 32 + wj + lan) * 32 + quad * 8);

#pragma unroll
        for (int mi = 0; mi < 4; ++mi) {
            acc[mi][0] = mfma16(af[mi], bfr[0], acc[mi][0]);
            acc[mi][1] = mfma16(af[mi], bfr[1], acc[mi][1]);
        }
        if (xseg) {
#pragma unroll
            for (int mi = 0; mi < 4; ++mi)
                acc[mi][2] = mfma16(af[mi], bfr[2], acc[mi][2]);
        } else {
#pragma unroll
            for (int mi = 0; mi < 4; ++mi)
                acc[mi][3] = mfma16(af[mi], bfr[2], acc[mi][3]);
        }
    }

    const int j = j0 + wj + lan;
    const float br = biases[j], bz = biases[512 + j];
    const float bi = biases[1024 + j], bh = biases[1536 + j];
#pragma unroll
    for (int mi = 0; mi < 4; ++mi) {
#pragma unroll
        for (int reg = 0; reg < 4; ++reg) {
            int m = m0 + wm + mi * 16 + quad * 4 + reg;
            float R  = acc[mi][0][reg] + br;
            float Z  = acc[mi][1][reg] + bz;
            float I  = acc[mi][2][reg] + bi;
            float HN = acc[mi][3][reg] + bh;
            float r = fast_sig(R);
            float z = fast_sig(Z);
            float nn = fast_tanh(I + r * HN);
            float hp = hprev[(size_t)m * H + j];
            float hv = (1.0f - z) * nn + z * hp;
            hout_f[(size_t)m * H + j] = hv;
            hout_b[(size_t)m * H + j] = f2bf(hv);
        }
    }
}

// ---------------- fused decoder d2+d3 ----------------
// p2 = tanh(p1 @ Wm2^T + bm2) [128 x 64]; out = p2 @ Wm3^T + bm3 -> out[b][t0+tl+1][:]
__global__ __launch_bounds__(256)
void d23_kernel(const uint16_t* __restrict__ p1,   // [M][512]
                const uint16_t* __restrict__ Wm2,  // [64][512]
                const float* __restrict__ bm2,
                const uint16_t* __restrict__ Wm3,  // [64][64]
                const float* __restrict__ bm3,
                float* __restrict__ out, int t0)
{
    __shared__ __align__(16) uint16_t As[128 * 32];  // 8 KB
    __shared__ __align__(16) uint16_t B2[64 * 32];   // 4 KB
    __shared__ __align__(16) uint16_t W3[64 * 64];   // 8 KB
    __shared__ __align__(16) uint16_t Ps[128 * 80];  // 20 KB (pad 80 avoids 0-mod-32 stride)

    const int tid = threadIdx.x;
    const int w = tid >> 6, l = tid & 63;
    const int quad = l >> 4, lan = l & 15;
    const int m0 = blockIdx.y * 128;
    const int wm = w * 32;

    // stage Wm3 once (drained by first loop barrier)
#pragma unroll
    for (int i = 0; i < 2; ++i) {
        int g = i * 256 + tid;
        int row = g >> 3, kc = (g & 7) * 8;
        load_lds16(Wm3 + (size_t)row * 64 + kc, W3 + (size_t)g * 8);
    }

    f32x4 acc[2][4];
#pragma unroll
    for (int i = 0; i < 2; ++i)
#pragma unroll
        for (int j = 0; j < 4; ++j) acc[i][j] = (f32x4){0.f, 0.f, 0.f, 0.f};

    for (int k0 = 0; k0 < 512; k0 += 32) {
        __syncthreads();
#pragma unroll
        for (int i = 0; i < 2; ++i) {
            int g = i * 256 + tid;
            int row = g >> 2, kc = (g & 3) * 8;
            load_lds16(p1 + (size_t)(m0 + row) * 512 + k0 + kc, As + (size_t)g * 8);
        }
        {
            int g = tid;
            int row = g >> 2, kc = (g & 3) * 8;
            load_lds16(Wm2 + (size_t)row * 512 + k0 + kc, B2 + (size_t)g * 8);
        }
        __syncthreads();

        bf16x8 af[2], bf[4];
#pragma unroll
        for (int mi = 0; mi < 2; ++mi)
            af[mi] = *(const bf16x8*)(As + (wm + mi * 16 + lan) * 32 + quad * 8);
#pragma unroll
        for (int nj = 0; nj < 4; ++nj)
            bf[nj] = *(const bf16x8*)(B2 + (nj * 16 + lan) * 32 + quad * 8);
#pragma unroll
        for (int mi = 0; mi < 2; ++mi)
#pragma unroll
            for (int nj = 0; nj < 4; ++nj)
                acc[mi][nj] = mfma16(af[mi], bf[nj], acc[mi][nj]);
    }

#pragma unroll
    for (int mi = 0; mi < 2; ++mi)
#pragma unroll
        for (int nj = 0; nj < 4; ++nj)
#pragma unroll
            for (int reg = 0; reg < 4; ++reg) {
                int row = wm + mi * 16 + quad * 4 + reg;
                int n = nj * 16 + lan;
                float v = fast_tanh(acc[mi][nj][reg] + bm2[n]);
                Ps[row * 80 + n] = f2bf(v);
            }
    __syncthreads();

    f32x4 a3[2][4];
#pragma unroll
    for (int i = 0; i < 2; ++i)
#pragma unroll
        for (int j = 0; j < 4; ++j) a3[i][j] = (f32x4){0.f, 0.f, 0.f, 0.f};

#pragma unroll
    for (int ks = 0; ks < 64; ks += 32) {
        bf16x8 af[2], bf[4];
#pragma unroll
        for (int mi = 0; mi < 2; ++mi)
            af[mi] = *(const bf16x8*)(Ps + (wm + mi * 16 + lan) * 80 + ks + quad * 8);
#pragma unroll
        for (int nj = 0; nj < 4; ++nj)
            bf[nj] = *(const bf16x8*)(W3 + (nj * 16 + lan) * 64 + ks + quad * 8);
#pragma unroll
        for (int mi = 0; mi < 2; ++mi)
#pragma unroll
            for (int nj = 0; nj < 4; ++nj)
                a3[mi][nj] = mfma16(af[mi], bf[nj], a3[mi][nj]);
    }

#pragma unroll
    for (int mi = 0; mi < 2; ++mi)
#pragma unroll
        for (int nj = 0; nj < 4; ++nj)
#pragma unroll
            for (int reg = 0; reg < 4; ++reg) {
                int m = m0 + wm + mi * 16 + quad * 4 + reg;
                int n = nj * 16 + lan;
                int b = m & (BATCH - 1), tl = m >> 12;
                out[(size_t)b * SEQL * A + (size_t)(t0 + tl + 1) * A + n] =
                    a3[mi][nj][reg] + bm3[n];
            }
}

// ---------------- host ----------------

extern "C" void kernel_launch(void* const* d_in, const int* in_sizes, int n_in,
                              void* d_out, int out_size, void* d_ws, size_t ws_size,
                              hipStream_t stream)
{
    const float* latent = (const float*)d_in[0];
    const float* target = (const float*)d_in[1];
    const float* Wd1 = (const float*)d_in[2];
    const float* bd1 = (const float*)d_in[3];
    const float* Wd2 = (const float*)d_in[4];
    const float* bd2 = (const float*)d_in[5];
    const float* Wd3 = (const float*)d_in[6];
    const float* bd3 = (const float*)d_in[7];
    const float* W_ih = (const float*)d_in[8];
    const float* W_hh = (const float*)d_in[9];
    const float* b_ih = (const float*)d_in[10];
    const float* b_hh = (const float*)d_in[11];
    const float* Wm1 = (const float*)d_in[12];
    const float* bm1 = (const float*)d_in[13];
    const float* Wm2 = (const float*)d_in[14];
    const float* bm2 = (const float*)d_in[15];
    const float* Wm3 = (const float*)d_in[16];
    const float* bm3 = (const float*)d_in[17];

    float* out = (float*)d_out;
    uint8_t* ws = (uint8_t*)d_ws;

    size_t off = 0;
    auto carve = [&](size_t bytes) { void* p = ws + off; off += (bytes + 255) & ~(size_t)255; return p; };
    uint16_t* latb = (uint16_t*)carve((size_t)BATCH * LATENT * 2);
    uint16_t* wd1b = (uint16_t*)carve((size_t)H * LATENT * 2);
    uint16_t* wd2b = (uint16_t*)carve((size_t)H * H * 2);
    uint16_t* wd3b = (uint16_t*)carve((size_t)H * H * 2);
    uint16_t* wm1b = (uint16_t*)carve((size_t)H * H * 2);
    uint16_t* wm2b = (uint16_t*)carve((size_t)A * H * 2);
    uint16_t* wm3b = (uint16_t*)carve((size_t)A * A * 2);
    uint16_t* wcat = (uint16_t*)carve((size_t)1536 * KCAT * 2);
    float* biases  = (float*)carve(2048 * 4);
    uint16_t* Xall = (uint16_t*)carve((size_t)NSTEP * BATCH * A * 2);  // 66.6 MB
    uint16_t* t1b  = (uint16_t*)carve((size_t)BATCH * H * 2);
    uint16_t* t2b  = (uint16_t*)carve((size_t)BATCH * H * 2);
    uint16_t* h0bf = (uint16_t*)carve((size_t)BATCH * H * 2);
    float* hA      = (float*)carve((size_t)BATCH * H * 4);
    float* hB      = (float*)carve((size_t)BATCH * H * 4);
    uint16_t* hall = (uint16_t*)carve((size_t)CT * BATCH * H * 2);     // 33.5 MB
    uint16_t* p1   = (uint16_t*)carve((size_t)CT * BATCH * H * 2);     // 33.5 MB
    float* hbuf[2] = {hA, hB};

    dim3 blk(256);

    // ---- prep ----
    auto cvt = [&](const float* s, uint16_t* d, int n) {
        cvt_bf16_kernel<<<dim3((n / 4 + 255) / 256), blk, 0, stream>>>(s, d, n);
    };
    cvt(latent, latb, BATCH * LATENT);
    cvt(Wd1, wd1b, H * LATENT);
    cvt(Wd2, wd2b, H * H);
    cvt(Wd3, wd3b, H * H);
    cvt(Wm1, wm1b, H * H);
    cvt(Wm2, wm2b, A * H);
    cvt(Wm3, wm3b, A * A);
    wcat_kernel<<<dim3((1536 * KCAT + 255) / 256), blk, 0, stream>>>(W_ih, W_hh, wcat);
    bias_kernel<<<dim3(8), blk, 0, stream>>>(b_ih, b_hh, biases);
    xall_kernel<<<dim3(NSTEP * BATCH * A / 4 / 256), blk, 0, stream>>>(target, Xall);
    bosout_kernel<<<dim3(BATCH * A / 256), blk, 0, stream>>>(out);

    // ---- initial MLP (latent -> h0) ----
    gemm_kernel<<<dim3(H / 128, BATCH / 128), blk, 0, stream>>>(
        latb, LATENT, wd1b, bd1, t1b, nullptr, H, LATENT, 1);
    gemm_kernel<<<dim3(H / 128, BATCH / 128), blk, 0, stream>>>(
        t1b, H, wd2b, bd2, t2b, nullptr, H, H, 1);
    gemm_kernel<<<dim3(H / 128, BATCH / 128), blk, 0, stream>>>(
        t2b, H, wd3b, bd3, h0bf, hA, H, H, 0);

    // ---- recurrence + chunked decoder ----
    for (int c = 0; c < 16; ++c) {
        const int ct = (c == 15) ? 7 : 8;
        const int M = ct * BATCH;
        for (int tl = 0; tl < ct; ++tl) {
            const int t = c * CT + tl;
            const uint16_t* hbf = (t == 0) ? h0bf : (hall + (size_t)((t - 1) & 7) * BATCH * H);
            gru_step_kernel<<<dim3(16, 32), blk, 0, stream>>>(
                Xall + (size_t)t * BATCH * A, hbf, wcat, biases,
                hbuf[t & 1], hbuf[(t + 1) & 1], hall + (size_t)tl * BATCH * H);
        }
        // d1 = tanh(h_chunk @ Wm1^T + bm1)  [M,512]
        gemm_kernel<<<dim3(H / 128, M / 128), blk, 0, stream>>>(
            hall, H, wm1b, bm1, p1, nullptr, H, H, 1);
        // d2+d3 fused -> out
        d23_kernel<<<dim3(1, M / 128), blk, 0, stream>>>(
            p1, wm2b, bm2, wm3b, bm3, out, c * CT);
    }
}